// Round 6
// baseline (138.233 us; speedup 1.0000x reference)
//
#include <hip/hip_runtime.h>

// TripletLoss batch-hard mining, N=8192, D=256, 64 classes, margin 0.3.
// R6: fix R5's latency-bound mine (17% occupancy, 0 VGPR headroom) and
// scatter-read prep.
//  - prep: LDS-staged relayout, ALL global accesses coalesced; X read once
//    (sq-norms via wave shuffle on the same data).
//  - mine: 512 blocks x 512 thr; wave = 32 rows x 512 cols => a[2][8]=32
//    VGPRs, ~64 regs of state total -> compiler can pipeline the 8 B-loads
//    per col-step; 2 blocks/CU = 4 waves/SIMD (50% occ). No LDS/barriers/
//    atomics in the hot loop; single-writer partials vp/vn[16][8192].
//  - finalizeA (32 blocks) reduces 16 slots/row + validity; finalizeB sums.

#define N_PTS 8192
#define DIM   256
#define MARGIN 0.3f

typedef __attribute__((ext_vector_type(8))) short bf16x8;
typedef __attribute__((ext_vector_type(4))) float f32x4;

__device__ __forceinline__ unsigned short f2bf(float f) {
    unsigned u = __float_as_uint(f);
    u += 0x7FFFu + ((u >> 16) & 1u);   // round-to-nearest-even
    return (unsigned short)(u >> 16);
}

// ---------------------------------------------------------------- prep ----
// 256 blocks x 256 thr; block = 32 rows (2 Rg of 16). Fragment-native output
// layout: ushort addr = Rg*4096 + kk*512 + lane*8  (lane = lgrp*16+lsub holds
// row lsub, k = kk*32 + lgrp*8 .. +8), so mine's fragment loads are 1KB
// contiguous wave-bursts.
__global__ __launch_bounds__(256)
void prep_kernel(const float* __restrict__ X,
                 unsigned short* __restrict__ Xb,
                 float* __restrict__ sq) {
    __shared__ unsigned short lds[32][264];   // +8 pad
    int t = threadIdx.x;
    int w = t >> 6, l = t & 63;
    int blk = blockIdx.x;
    int row0 = blk * 32;
    // read: wave w, iter i -> row i*4+w; lane l reads float4 k-chunk l (coalesced)
    #pragma unroll
    for (int i = 0; i < 8; ++i) {
        int r = i * 4 + w;
        float4 v = reinterpret_cast<const float4*>(X)[(size_t)(row0 + r) * 64 + l];
        ushort4 b;
        b.x = f2bf(v.x); b.y = f2bf(v.y); b.z = f2bf(v.z); b.w = f2bf(v.w);
        *reinterpret_cast<ushort4*>(&lds[r][l * 4]) = b;
        float p = v.x * v.x + v.y * v.y + v.z * v.z + v.w * v.w;
        #pragma unroll
        for (int m = 1; m < 64; m <<= 1) p += __shfl_xor(p, m, 64);
        if (l == 0) sq[row0 + r] = p;
    }
    __syncthreads();
    // write: 2048 ushort4, 8 per thread, fully coalesced global stores
    #pragma unroll
    for (int j = 0; j < 8; ++j) {
        int i = j * 256 + t;          // 0..2047
        int ii = i & 1023;
        int Rg = i >> 10;
        int kk = ii >> 7;
        int ll = (ii >> 1) & 63;
        int half = ii & 1;
        int r = Rg * 16 + (ll & 15);
        int k = kk * 32 + (ll >> 4) * 8 + half * 4;
        ushort4 b = *reinterpret_cast<const ushort4*>(&lds[r][k]);
        reinterpret_cast<ushort4*>(Xb)[(size_t)blk * 2048 + i] = b;
    }
}

// ---------------------------------------------------------------- mine ----
__launch_bounds__(512, 4)
__global__ void mine_kernel(const unsigned short* __restrict__ Xb,
                            const float* __restrict__ sq,
                            const int* __restrict__ labels,
                            float* __restrict__ vp,
                            float* __restrict__ vn) {
    int bid = blockIdx.x;
    // XCD swizzle: 512 = 8*64, bijective
    int swz = (bid & 7) * 64 + (bid >> 3);
    int panel = swz >> 3;            // 64 row-panels of 128
    int e     = swz & 7;             // col-eighth of 1024
    int tid = threadIdx.x;
    int w = tid >> 6, l = tid & 63;
    int wr = w >> 1, wc = w & 1;     // 4 row-waves x 2 col-halves
    int lsub = l & 15, lgrp = l >> 4;

    const float INF = __int_as_float(0x7f800000);

    // A-panel: 32 rows x K=256 in 32 VGPRs. Rg(m) = panel*8 + wr*2 + m.
    const unsigned short* abase = Xb + (size_t)(panel * 8 + wr * 2) * 4096 + l * 8;
    bf16x8 a[2][8];
    #pragma unroll
    for (int m = 0; m < 2; ++m)
        #pragma unroll
        for (int kk = 0; kk < 8; ++kk)
            a[m][kk] = *reinterpret_cast<const bf16x8*>(abase + m * 4096 + kk * 512);

    int rowbase = panel * 128 + wr * 32;
    int lrj[2][4];
    #pragma unroll
    for (int m = 0; m < 2; ++m)
        #pragma unroll
        for (int j = 0; j < 4; ++j)
            lrj[m][j] = labels[rowbase + m * 16 + lgrp * 4 + j];

    float vpr[2][4], vnr[2][4];      // running max/min of (sc - 2*dot)
    #pragma unroll
    for (int m = 0; m < 2; ++m)
        #pragma unroll
        for (int j = 0; j < 4; ++j) { vpr[m][j] = -INF; vnr[m][j] = INF; }

    int colwave = e * 1024 + wc * 512;
    const unsigned short* bbase = Xb + (size_t)(colwave >> 4) * 4096 + l * 8;

    for (int cs = 0; cs < 16; ++cs) {          // 16 col-steps of 32
        int colbase = colwave + cs * 32;
        int lc0 = labels[colbase + lsub];
        int lc1 = labels[colbase + 16 + lsub];
        float sc0 = sq[colbase + lsub];
        float sc1 = sq[colbase + 16 + lsub];

        f32x4 acc[2][2];
        #pragma unroll
        for (int m = 0; m < 2; ++m) {
            acc[m][0] = (f32x4){0.f, 0.f, 0.f, 0.f};
            acc[m][1] = (f32x4){0.f, 0.f, 0.f, 0.f};
        }

        const unsigned short* bb = bbase + (size_t)cs * 8192;
        #pragma unroll
        for (int kp = 0; kp < 4; ++kp) {       // 2 kk per kp
            bf16x8 b00 = *reinterpret_cast<const bf16x8*>(bb + kp * 1024);
            bf16x8 b01 = *reinterpret_cast<const bf16x8*>(bb + 4096 + kp * 1024);
            bf16x8 b10 = *reinterpret_cast<const bf16x8*>(bb + kp * 1024 + 512);
            bf16x8 b11 = *reinterpret_cast<const bf16x8*>(bb + 4096 + kp * 1024 + 512);
            #pragma unroll
            for (int m = 0; m < 2; ++m) {
                acc[m][0] = __builtin_amdgcn_mfma_f32_16x16x32_bf16(
                    a[m][2 * kp], b00, acc[m][0], 0, 0, 0);
                acc[m][1] = __builtin_amdgcn_mfma_f32_16x16x32_bf16(
                    a[m][2 * kp], b01, acc[m][1], 0, 0, 0);
            }
            #pragma unroll
            for (int m = 0; m < 2; ++m) {
                acc[m][0] = __builtin_amdgcn_mfma_f32_16x16x32_bf16(
                    a[m][2 * kp + 1], b10, acc[m][0], 0, 0, 0);
                acc[m][1] = __builtin_amdgcn_mfma_f32_16x16x32_bf16(
                    a[m][2 * kp + 1], b11, acc[m][1], 0, 0, 0);
            }
        }

        // fold: val = sc - 2*dot; max over same-label, min over diff-label.
        #pragma unroll
        for (int m = 0; m < 2; ++m)
            #pragma unroll
            for (int j = 0; j < 4; ++j) {
                int lr = lrj[m][j];
                float v0 = fmaf(-2.f, acc[m][0][j], sc0);
                float v1 = fmaf(-2.f, acc[m][1][j], sc1);
                bool s0 = (lr == lc0), s1 = (lr == lc1);
                vpr[m][j] = fmaxf(vpr[m][j], s0 ? v0 : -INF);
                vpr[m][j] = fmaxf(vpr[m][j], s1 ? v1 : -INF);
                vnr[m][j] = fminf(vnr[m][j], s0 ? INF : v0);
                vnr[m][j] = fminf(vnr[m][j], s1 ? INF : v1);
            }
    }

    // reduce over the 16 lsub lanes; single-writer partial slot.
    int slot = e * 2 + wc;           // 0..15
    #pragma unroll
    for (int m = 0; m < 2; ++m)
        #pragma unroll
        for (int j = 0; j < 4; ++j) {
            float p = vpr[m][j], n = vnr[m][j];
            #pragma unroll
            for (int s = 1; s < 16; s <<= 1) {
                p = fmaxf(p, __shfl_xor(p, s, 64));
                n = fminf(n, __shfl_xor(n, s, 64));
            }
            if (lsub == 0) {
                int row = rowbase + m * 16 + lgrp * 4 + j;
                vp[slot * N_PTS + row] = p;
                vn[slot * N_PTS + row] = n;
            }
        }
}

// ------------------------------------------------------------ finalizeA ----
__global__ void finalizeA_kernel(const float* __restrict__ vp,
                                 const float* __restrict__ vn,
                                 const float* __restrict__ sq,
                                 const int* __restrict__ labels,
                                 float* __restrict__ bsum,
                                 float* __restrict__ bcnt) {
    __shared__ int hist[64];
    __shared__ float ss[4], cc[4];
    int tid = threadIdx.x;
    if (tid < 64) hist[tid] = 0;
    __syncthreads();
    for (int i = tid; i < N_PTS; i += 256) atomicAdd(&hist[labels[i]], 1);
    __syncthreads();

    const float INF = __int_as_float(0x7f800000);
    int r = blockIdx.x * 256 + tid;
    float mp = -INF, mn = INF;
    #pragma unroll
    for (int s = 0; s < 16; ++s) {
        mp = fmaxf(mp, vp[s * N_PTS + r]);
        mn = fminf(mn, vn[s * N_PTS + r]);
    }
    float sr = sq[r];
    float hp2 = sr + mp;                    // hardest-pos d^2 (unclamped)
    float hn2 = fmaxf(sr + mn, 0.f);        // hardest-neg d^2, clamped
    int h = hist[labels[r]];
    bool valid = (h > 1) && (h < N_PTS) && (hp2 > 0.f);
    float contrib = valid ? fmaxf(sqrtf(hp2) - sqrtf(hn2) + MARGIN, 0.f) : 0.f;
    float cnt = valid ? 1.f : 0.f;

    #pragma unroll
    for (int m = 1; m < 64; m <<= 1) {
        contrib += __shfl_xor(contrib, m, 64);
        cnt     += __shfl_xor(cnt, m, 64);
    }
    int wv = tid >> 6, lv = tid & 63;
    if (lv == 0) { ss[wv] = contrib; cc[wv] = cnt; }
    __syncthreads();
    if (tid == 0) {
        bsum[blockIdx.x] = ss[0] + ss[1] + ss[2] + ss[3];
        bcnt[blockIdx.x] = cc[0] + cc[1] + cc[2] + cc[3];
    }
}

// ------------------------------------------------------------ finalizeB ----
__global__ void finalizeB_kernel(const float* __restrict__ bsum,
                                 const float* __restrict__ bcnt,
                                 float* __restrict__ out) {
    int l = threadIdx.x;
    float s = (l < 32) ? bsum[l] : 0.f;
    float c = (l < 32) ? bcnt[l] : 0.f;
    #pragma unroll
    for (int m = 1; m < 64; m <<= 1) {
        s += __shfl_xor(s, m, 64);
        c += __shfl_xor(c, m, 64);
    }
    if (l == 0) out[0] = (c > 0.f) ? (s / c) : 0.f;
}

// -------------------------------------------------------------- launch ----
extern "C" void kernel_launch(void* const* d_in, const int* in_sizes, int n_in,
                              void* d_out, int out_size, void* d_ws, size_t ws_size,
                              hipStream_t stream) {
    const float* X      = (const float*)d_in[0];
    const int*   labels = (const int*)d_in[1];
    float*       out    = (float*)d_out;

    char* ws = (char*)d_ws;
    unsigned short* Xb = (unsigned short*)ws;                    // 4 MB
    float* sq   = (float*)(ws + 4194304);                        // 32 KB
    float* vp   = (float*)(ws + 4194304 + 32768);                // 512 KB
    float* vn   = (float*)(ws + 4194304 + 32768 + 524288);       // 512 KB
    float* bsum = (float*)(ws + 4194304 + 32768 + 1048576);      // 128 B
    float* bcnt = (float*)(ws + 4194304 + 32768 + 1048576 + 128);

    prep_kernel<<<256, 256, 0, stream>>>(X, Xb, sq);
    mine_kernel<<<512, 512, 0, stream>>>(Xb, sq, labels, vp, vn);
    finalizeA_kernel<<<32, 256, 0, stream>>>(vp, vn, sq, labels, bsum, bcnt);
    finalizeB_kernel<<<1, 64, 0, stream>>>(bsum, bcnt, out);
}

// Round 9
// 123.310 us; speedup vs baseline: 1.1210x; 1.1210x over previous
//
#include <hip/hip_runtime.h>

// TripletLoss batch-hard mining, N=8192, D=256, 64 classes, margin 0.3.
// R7 (3rd submit — R7/R8 benches were GPU-acquisition timeouts, no data):
// B-persistent / A-streamed mine.
//  - Wave owns 64 cols x K=256 in 128 VGPRs (B loaded ONCE from global:
//    total B traffic 4 MB vs R5's 512 MB). Block = 8 waves = 512 cols x
//    one 512-row band; sweeps 8 A-chunks (64 rows x 256k, 32 KB) through
//    double-buffered XOR-swizzled LDS via global_load_lds.
//  - Mining flipped to col-anchors (wave-private cols): running
//    max/min(sr - 2*dot) in 8 regs; no stores/atomics in the loop; one
//    coalesced partial write at the end -> vp/vn[16][8192] (1 MB).
//  - prep: trivial coalesced fp32->bf16 (row-major) + row norms + zero-init
//    of the reduction scalars.
//  - finalize: single kernel (32 blocks): hist + per-col validity/contrib,
//    block sums via global atomicAdd, ticket -> last block writes out.

#define N_PTS 8192
#define DIM   256
#define MARGIN 0.3f

typedef __attribute__((ext_vector_type(8))) short bf16x8;
typedef __attribute__((ext_vector_type(4))) float f32x4;

__device__ __forceinline__ unsigned short f2bf(float f) {
    unsigned u = __float_as_uint(f);
    u += 0x7FFFu + ((u >> 16) & 1u);   // round-to-nearest-even
    return (unsigned short)(u >> 16);
}

// ---------------------------------------------------------------- prep ----
// t-th float4 -> t-th ushort4 (row-major bf16 copy, fully coalesced) +
// wave-per-row sq-norm. Block 0 zero-inits gsum/gcnt/ticket.
__global__ __launch_bounds__(256)
void prep_kernel(const float* __restrict__ X,
                 unsigned short* __restrict__ Xb,
                 float* __restrict__ sq,
                 float* __restrict__ gsum) {     // gsum[0], gcnt[1], ticket[2]
    int t = blockIdx.x * 256 + threadIdx.x;      // t = row*64 + lane
    int row = t >> 6, lane = t & 63;
    float4 v = reinterpret_cast<const float4*>(X)[t];
    ushort4 b4;
    b4.x = f2bf(v.x); b4.y = f2bf(v.y); b4.z = f2bf(v.z); b4.w = f2bf(v.w);
    reinterpret_cast<ushort4*>(Xb)[t] = b4;
    float p = v.x * v.x + v.y * v.y + v.z * v.z + v.w * v.w;
    #pragma unroll
    for (int m = 1; m < 64; m <<= 1) p += __shfl_xor(p, m, 64);
    if (lane == 0) sq[row] = p;
    if (blockIdx.x == 0 && threadIdx.x < 3)
        gsum[threadIdx.x] = 0.f;                 // gsum, gcnt, ticket(=0 bits)
}

// ---------------------------------------------------------------- mine ----
// grid 256 = 16 col-groups x 16 row-bands (XCD-swizzled). 512 thr = 8 waves,
// wave w owns cols [cg*512 + w*64, +64). B-frags b[n][kk] (128 VGPR) loaded
// once. Loop: 8 A-chunks of 64 rows staged to LDS (dbuf, 16B-chunk XOR
// swizzle slot = kc ^ (row&7): 2-way max on ds_read_b128, free). 128 MFMA
// per chunk per wave; fold updates per-col running max/min of (sr - 2*dot).
__launch_bounds__(512, 2)
__global__ void mine_kernel(const unsigned short* __restrict__ Xb,
                            const float* __restrict__ sq,
                            const int* __restrict__ labels,
                            float* __restrict__ vp,
                            float* __restrict__ vn) {
    __shared__ unsigned short buf[2][64 * 256];  // 2 x 32 KB

    int bid = blockIdx.x;
    int swz = (bid & 7) * 32 + (bid >> 3);       // 256 = 8*32, bijective
    int cg = swz >> 4;                           // col-group (512 cols)
    int rb = swz & 15;                           // row-band (512 rows)

    int tid = threadIdx.x;
    int w = tid >> 6, l = tid & 63;
    int lsub = l & 15, lgrp = l >> 4;
    int C0 = cg * 512 + w * 64;

    const float INF = __int_as_float(0x7f800000);

    // ---- B-panel: 64 cols x K=256 in registers (one-time scatter load) ----
    bf16x8 b[4][8];
    {
        const unsigned short* pb = Xb + (size_t)(C0 + lsub) * DIM + lgrp * 8;
        #pragma unroll
        for (int n = 0; n < 4; ++n)
            #pragma unroll
            for (int kk = 0; kk < 8; ++kk)
                b[n][kk] = *reinterpret_cast<const bf16x8*>(
                    pb + (size_t)n * 16 * DIM + kk * 32);
    }
    int lc4[4];
    #pragma unroll
    for (int n = 0; n < 4; ++n) lc4[n] = labels[C0 + n * 16 + lsub];

    float hpc[4], hnc[4];            // running max/min of (sr - 2*dot)
    #pragma unroll
    for (int n = 0; n < 4; ++n) { hpc[n] = -INF; hnc[n] = INF; }

    int band = rb * 512;
    int xorv = lsub & 7;

    // ---- stage chunk 0 ----
    {
        const unsigned short* src = Xb + (size_t)band * DIM;
        #pragma unroll
        for (int i = 0; i < 4; ++i) {
            int p = i * 512 + tid;
            int row = p >> 5, slot = p & 31;
            int kc = slot ^ (row & 7);
            __builtin_amdgcn_global_load_lds(
                (const __attribute__((address_space(1))) void*)(src + row * DIM + kc * 8),
                (__attribute__((address_space(3))) void*)(&buf[0][p * 8]),
                16, 0, 0);
        }
    }
    __syncthreads();

    int cur = 0;
    for (int c = 0; c < 8; ++c) {
        // issue next-chunk stage (overlaps with compute; drained at barrier)
        if (c < 7) {
            const unsigned short* src = Xb + (size_t)(band + (c + 1) * 64) * DIM;
            #pragma unroll
            for (int i = 0; i < 4; ++i) {
                int p = i * 512 + tid;
                int row = p >> 5, slot = p & 31;
                int kc = slot ^ (row & 7);
                __builtin_amdgcn_global_load_lds(
                    (const __attribute__((address_space(1))) void*)(src + row * DIM + kc * 8),
                    (__attribute__((address_space(3))) void*)(&buf[cur ^ 1][p * 8]),
                    16, 0, 0);
            }
        }

        // ---- compute: 64 rows x 64 cols, K=256 ----
        const unsigned short* bc = buf[cur];
        f32x4 acc[4][4];
        #pragma unroll
        for (int m = 0; m < 4; ++m)
            #pragma unroll
            for (int n = 0; n < 4; ++n) acc[m][n] = (f32x4){0.f, 0.f, 0.f, 0.f};

        #pragma unroll
        for (int kk = 0; kk < 8; ++kk) {
            bf16x8 a[4];
            #pragma unroll
            for (int m = 0; m < 4; ++m) {
                int rowA = m * 16 + lsub;
                int slot = (kk * 4 + lgrp) ^ xorv;
                a[m] = *reinterpret_cast<const bf16x8*>(&bc[rowA * 256 + slot * 8]);
            }
            #pragma unroll
            for (int m = 0; m < 4; ++m)
                #pragma unroll
                for (int n = 0; n < 4; ++n)
                    acc[m][n] = __builtin_amdgcn_mfma_f32_16x16x32_bf16(
                        a[m], b[n][kk], acc[m][n], 0, 0, 0);
        }

        // ---- fold into col-anchor running partials ----
        // acc[m][n][j]: row = c*64 + m*16 + lgrp*4 + j, col = n*16 + lsub.
        int rowg = band + c * 64 + lgrp * 4;
        #pragma unroll
        for (int m = 0; m < 4; ++m)
            #pragma unroll
            for (int j = 0; j < 4; ++j) {
                int gr = rowg + m * 16 + j;
                int lr = labels[gr];
                float sr = sq[gr];
                #pragma unroll
                for (int n = 0; n < 4; ++n) {
                    float v = fmaf(-2.f, acc[m][n][j], sr);
                    bool same = (lr == lc4[n]);
                    hpc[n] = same ? fmaxf(hpc[n], v) : hpc[n];
                    hnc[n] = same ? hnc[n] : fminf(hnc[n], v);
                }
            }

        if (c < 7) __syncthreads();   // stage(c+1) done + all reads of cur done
        cur ^= 1;
    }

    // ---- reduce over the 4 lgrp replicas; one coalesced partial write ----
    #pragma unroll
    for (int n = 0; n < 4; ++n) {
        float p = hpc[n], q = hnc[n];
        p = fmaxf(p, __shfl_xor(p, 16, 64));
        q = fminf(q, __shfl_xor(q, 16, 64));
        p = fmaxf(p, __shfl_xor(p, 32, 64));
        q = fminf(q, __shfl_xor(q, 32, 64));
        if (l < 16) {
            int col = C0 + n * 16 + l;
            vp[rb * N_PTS + col] = p;
            vn[rb * N_PTS + col] = q;
        }
    }
}

// ------------------------------------------------------------ finalize ----
// 32 blocks x 256: anchor = col. Combine 16 row-band partials, validity,
// contrib; block sums -> global atomicAdd; ticketed last block writes out.
__global__ void finalize_kernel(const float* __restrict__ vp,
                                const float* __restrict__ vn,
                                const float* __restrict__ sq,
                                const int* __restrict__ labels,
                                float* __restrict__ gsum,   // [0]=sum [1]=cnt [2]=ticket
                                float* __restrict__ out) {
    __shared__ int hist[64];
    __shared__ float ss[4], cc[4];
    int tid = threadIdx.x;
    if (tid < 64) hist[tid] = 0;
    __syncthreads();
    for (int i = tid; i < N_PTS; i += 256) atomicAdd(&hist[labels[i]], 1);
    __syncthreads();

    const float INF = __int_as_float(0x7f800000);
    int c = blockIdx.x * 256 + tid;
    float mp = -INF, mn = INF;
    #pragma unroll
    for (int s = 0; s < 16; ++s) {
        mp = fmaxf(mp, vp[s * N_PTS + c]);
        mn = fminf(mn, vn[s * N_PTS + c]);
    }
    float sc = sq[c];
    float hp2 = sc + mp;                 // hardest-pos d^2 (unclamped)
    float hn2 = fmaxf(sc + mn, 0.f);     // hardest-neg d^2, clamped
    int h = hist[labels[c]];
    bool valid = (h > 1) && (hp2 > 0.f); // neg always exists (64 classes)
    float contrib = valid ? fmaxf(sqrtf(hp2) - sqrtf(hn2) + MARGIN, 0.f) : 0.f;
    float cnt = valid ? 1.f : 0.f;

    #pragma unroll
    for (int m = 1; m < 64; m <<= 1) {
        contrib += __shfl_xor(contrib, m, 64);
        cnt     += __shfl_xor(cnt, m, 64);
    }
    int wv = tid >> 6, lv = tid & 63;
    if (lv == 0) { ss[wv] = contrib; cc[wv] = cnt; }
    __syncthreads();
    if (tid == 0) {
        atomicAdd(&gsum[0], ss[0] + ss[1] + ss[2] + ss[3]);
        atomicAdd(&gsum[1], cc[0] + cc[1] + cc[2] + cc[3]);
        __threadfence();
        unsigned old = atomicAdd(reinterpret_cast<unsigned*>(&gsum[2]), 1u);
        if (old == 31u) {                // last block: publish result
            float S = atomicAdd(&gsum[0], 0.f);
            float C = atomicAdd(&gsum[1], 0.f);
            out[0] = (C > 0.f) ? (S / C) : 0.f;
        }
    }
}

// -------------------------------------------------------------- launch ----
extern "C" void kernel_launch(void* const* d_in, const int* in_sizes, int n_in,
                              void* d_out, int out_size, void* d_ws, size_t ws_size,
                              hipStream_t stream) {
    const float* X      = (const float*)d_in[0];
    const int*   labels = (const int*)d_in[1];
    float*       out    = (float*)d_out;

    char* ws = (char*)d_ws;
    unsigned short* Xb = (unsigned short*)ws;                    // 4 MB
    float* sq   = (float*)(ws + 4194304);                        // 32 KB
    float* vp   = (float*)(ws + 4194304 + 32768);                // 512 KB
    float* vn   = (float*)(ws + 4194304 + 32768 + 524288);       // 512 KB
    float* gsum = (float*)(ws + 4194304 + 32768 + 1048576);      // 12 B

    prep_kernel<<<2048, 256, 0, stream>>>(X, Xb, sq, gsum);
    mine_kernel<<<256, 512, 0, stream>>>(Xb, sq, labels, vp, vn);
    finalize_kernel<<<32, 256, 0, stream>>>(vp, vn, sq, labels, gsum, out);
}

// Round 10
// 120.116 us; speedup vs baseline: 1.1508x; 1.0266x over previous
//
#include <hip/hip_runtime.h>

// TripletLoss batch-hard mining, N=8192, D=256, 64 classes, margin 0.3.
// R10: R9 structure (B-persistent / A-streamed) with two targeted fixes:
//  1. __launch_bounds__(512,1): R9's (512,2) was treated as an occupancy
//     floor that capped VGPRs at 128 and spilled ~20 regs (WRITE_SIZE
//     11MB vs 1MB of real output). Demand ~230 regs -> let it have them
//     (2 waves/SIMD, no spill).
//  2. Band meta (sq,label) staged to LDS float2[512] at block start; the
//     fold's 256 per-thread global scalar loads become broadcast
//     ds_read_b64 -> no vmcnt stalls in the hot loop.

#define N_PTS 8192
#define DIM   256
#define MARGIN 0.3f

typedef __attribute__((ext_vector_type(8))) short bf16x8;
typedef __attribute__((ext_vector_type(4))) float f32x4;

__device__ __forceinline__ unsigned short f2bf(float f) {
    unsigned u = __float_as_uint(f);
    u += 0x7FFFu + ((u >> 16) & 1u);   // round-to-nearest-even
    return (unsigned short)(u >> 16);
}

// ---------------------------------------------------------------- prep ----
// t-th float4 -> t-th ushort4 (row-major bf16 copy, fully coalesced) +
// wave-per-row sq-norm. Block 0 zero-inits gsum/gcnt/ticket.
__global__ __launch_bounds__(256)
void prep_kernel(const float* __restrict__ X,
                 unsigned short* __restrict__ Xb,
                 float* __restrict__ sq,
                 float* __restrict__ gsum) {     // gsum[0], gcnt[1], ticket[2]
    int t = blockIdx.x * 256 + threadIdx.x;      // t = row*64 + lane
    int row = t >> 6, lane = t & 63;
    float4 v = reinterpret_cast<const float4*>(X)[t];
    ushort4 b4;
    b4.x = f2bf(v.x); b4.y = f2bf(v.y); b4.z = f2bf(v.z); b4.w = f2bf(v.w);
    reinterpret_cast<ushort4*>(Xb)[t] = b4;
    float p = v.x * v.x + v.y * v.y + v.z * v.z + v.w * v.w;
    #pragma unroll
    for (int m = 1; m < 64; m <<= 1) p += __shfl_xor(p, m, 64);
    if (lane == 0) sq[row] = p;
    if (blockIdx.x == 0 && threadIdx.x < 3)
        gsum[threadIdx.x] = 0.f;                 // gsum, gcnt, ticket(=0 bits)
}

// ---------------------------------------------------------------- mine ----
// grid 256 = 16 col-groups x 16 row-bands (XCD-swizzled). 512 thr = 8 waves,
// wave w owns cols [cg*512 + w*64, +64). B-frags b[n][kk] (128 VGPR) loaded
// once. Loop: 8 A-chunks of 64 rows staged to LDS (dbuf, 16B-chunk XOR
// swizzle) via global_load_lds. 128 MFMA per chunk per wave; fold updates
// per-col running max/min of (sr - 2*dot) using LDS-resident band meta.
__launch_bounds__(512, 1)
__global__ void mine_kernel(const unsigned short* __restrict__ Xb,
                            const float* __restrict__ sq,
                            const int* __restrict__ labels,
                            float* __restrict__ vp,
                            float* __restrict__ vn) {
    __shared__ unsigned short buf[2][64 * 256];  // 2 x 32 KB
    __shared__ float2 meta[512];                 // (sq, label-bits) per band row

    int bid = blockIdx.x;
    int swz = (bid & 7) * 32 + (bid >> 3);       // 256 = 8*32, bijective
    int cg = swz >> 4;                           // col-group (512 cols)
    int rb = swz & 15;                           // row-band (512 rows)

    int tid = threadIdx.x;
    int w = tid >> 6, l = tid & 63;
    int lsub = l & 15, lgrp = l >> 4;
    int C0 = cg * 512 + w * 64;
    int band = rb * 512;

    const float INF = __int_as_float(0x7f800000);

    // ---- band meta -> LDS (one coalesced load per thread) ----
    meta[tid] = make_float2(sq[band + tid],
                            __int_as_float(labels[band + tid]));

    // ---- B-panel: 64 cols x K=256 in registers (one-time scatter load) ----
    bf16x8 b[4][8];
    {
        const unsigned short* pb = Xb + (size_t)(C0 + lsub) * DIM + lgrp * 8;
        #pragma unroll
        for (int n = 0; n < 4; ++n)
            #pragma unroll
            for (int kk = 0; kk < 8; ++kk)
                b[n][kk] = *reinterpret_cast<const bf16x8*>(
                    pb + (size_t)n * 16 * DIM + kk * 32);
    }
    int lc4[4];
    #pragma unroll
    for (int n = 0; n < 4; ++n) lc4[n] = labels[C0 + n * 16 + lsub];

    float hpc[4], hnc[4];            // running max/min of (sr - 2*dot)
    #pragma unroll
    for (int n = 0; n < 4; ++n) { hpc[n] = -INF; hnc[n] = INF; }

    int xorv = lsub & 7;

    // ---- stage chunk 0 ----
    {
        const unsigned short* src = Xb + (size_t)band * DIM;
        #pragma unroll
        for (int i = 0; i < 4; ++i) {
            int p = i * 512 + tid;
            int row = p >> 5, slot = p & 31;
            int kc = slot ^ (row & 7);
            __builtin_amdgcn_global_load_lds(
                (const __attribute__((address_space(1))) void*)(src + row * DIM + kc * 8),
                (__attribute__((address_space(3))) void*)(&buf[0][p * 8]),
                16, 0, 0);
        }
    }
    __syncthreads();   // covers meta writes + chunk-0 staging

    int cur = 0;
    for (int c = 0; c < 8; ++c) {
        // issue next-chunk stage (overlaps with compute; drained at barrier)
        if (c < 7) {
            const unsigned short* src = Xb + (size_t)(band + (c + 1) * 64) * DIM;
            #pragma unroll
            for (int i = 0; i < 4; ++i) {
                int p = i * 512 + tid;
                int row = p >> 5, slot = p & 31;
                int kc = slot ^ (row & 7);
                __builtin_amdgcn_global_load_lds(
                    (const __attribute__((address_space(1))) void*)(src + row * DIM + kc * 8),
                    (__attribute__((address_space(3))) void*)(&buf[cur ^ 1][p * 8]),
                    16, 0, 0);
            }
        }

        // ---- compute: 64 rows x 64 cols, K=256 ----
        const unsigned short* bc = buf[cur];
        f32x4 acc[4][4];
        #pragma unroll
        for (int m = 0; m < 4; ++m)
            #pragma unroll
            for (int n = 0; n < 4; ++n) acc[m][n] = (f32x4){0.f, 0.f, 0.f, 0.f};

        #pragma unroll
        for (int kk = 0; kk < 8; ++kk) {
            bf16x8 a[4];
            #pragma unroll
            for (int m = 0; m < 4; ++m) {
                int rowA = m * 16 + lsub;
                int slot = (kk * 4 + lgrp) ^ xorv;
                a[m] = *reinterpret_cast<const bf16x8*>(&bc[rowA * 256 + slot * 8]);
            }
            #pragma unroll
            for (int m = 0; m < 4; ++m)
                #pragma unroll
                for (int n = 0; n < 4; ++n)
                    acc[m][n] = __builtin_amdgcn_mfma_f32_16x16x32_bf16(
                        a[m], b[n][kk], acc[m][n], 0, 0, 0);
        }

        // ---- fold into col-anchor running partials (meta from LDS) ----
        // acc[m][n][j]: row = c*64 + m*16 + lgrp*4 + j, col = n*16 + lsub.
        int rloc = c * 64 + lgrp * 4;
        #pragma unroll
        for (int m = 0; m < 4; ++m)
            #pragma unroll
            for (int j = 0; j < 4; ++j) {
                float2 md = meta[rloc + m * 16 + j];
                float sr = md.x;
                int lr = __float_as_int(md.y);
                #pragma unroll
                for (int n = 0; n < 4; ++n) {
                    float v = fmaf(-2.f, acc[m][n][j], sr);
                    bool same = (lr == lc4[n]);
                    hpc[n] = fmaxf(hpc[n], same ? v : -INF);
                    hnc[n] = fminf(hnc[n], same ? INF : v);
                }
            }

        if (c < 7) __syncthreads();   // stage(c+1) done + all reads of cur done
        cur ^= 1;
    }

    // ---- reduce over the 4 lgrp replicas; one coalesced partial write ----
    #pragma unroll
    for (int n = 0; n < 4; ++n) {
        float p = hpc[n], q = hnc[n];
        p = fmaxf(p, __shfl_xor(p, 16, 64));
        q = fminf(q, __shfl_xor(q, 16, 64));
        p = fmaxf(p, __shfl_xor(p, 32, 64));
        q = fminf(q, __shfl_xor(q, 32, 64));
        if (l < 16) {
            int col = C0 + n * 16 + l;
            vp[rb * N_PTS + col] = p;
            vn[rb * N_PTS + col] = q;
        }
    }
}

// ------------------------------------------------------------ finalize ----
// 32 blocks x 256: anchor = col. Combine 16 row-band partials, validity,
// contrib; block sums -> global atomicAdd; ticketed last block writes out.
__global__ void finalize_kernel(const float* __restrict__ vp,
                                const float* __restrict__ vn,
                                const float* __restrict__ sq,
                                const int* __restrict__ labels,
                                float* __restrict__ gsum,   // [0]=sum [1]=cnt [2]=ticket
                                float* __restrict__ out) {
    __shared__ int hist[64];
    __shared__ float ss[4], cc[4];
    int tid = threadIdx.x;
    if (tid < 64) hist[tid] = 0;
    __syncthreads();
    for (int i = tid; i < N_PTS; i += 256) atomicAdd(&hist[labels[i]], 1);
    __syncthreads();

    const float INF = __int_as_float(0x7f800000);
    int c = blockIdx.x * 256 + tid;
    float mp = -INF, mn = INF;
    #pragma unroll
    for (int s = 0; s < 16; ++s) {
        mp = fmaxf(mp, vp[s * N_PTS + c]);
        mn = fminf(mn, vn[s * N_PTS + c]);
    }
    float sc = sq[c];
    float hp2 = sc + mp;                 // hardest-pos d^2 (unclamped)
    float hn2 = fmaxf(sc + mn, 0.f);     // hardest-neg d^2, clamped
    int h = hist[labels[c]];
    bool valid = (h > 1) && (hp2 > 0.f); // neg always exists (64 classes)
    float contrib = valid ? fmaxf(sqrtf(hp2) - sqrtf(hn2) + MARGIN, 0.f) : 0.f;
    float cnt = valid ? 1.f : 0.f;

    #pragma unroll
    for (int m = 1; m < 64; m <<= 1) {
        contrib += __shfl_xor(contrib, m, 64);
        cnt     += __shfl_xor(cnt, m, 64);
    }
    int wv = tid >> 6, lv = tid & 63;
    if (lv == 0) { ss[wv] = contrib; cc[wv] = cnt; }
    __syncthreads();
    if (tid == 0) {
        atomicAdd(&gsum[0], ss[0] + ss[1] + ss[2] + ss[3]);
        atomicAdd(&gsum[1], cc[0] + cc[1] + cc[2] + cc[3]);
        __threadfence();
        unsigned old = atomicAdd(reinterpret_cast<unsigned*>(&gsum[2]), 1u);
        if (old == 31u) {                // last block: publish result
            float S = atomicAdd(&gsum[0], 0.f);
            float C = atomicAdd(&gsum[1], 0.f);
            out[0] = (C > 0.f) ? (S / C) : 0.f;
        }
    }
}

// -------------------------------------------------------------- launch ----
extern "C" void kernel_launch(void* const* d_in, const int* in_sizes, int n_in,
                              void* d_out, int out_size, void* d_ws, size_t ws_size,
                              hipStream_t stream) {
    const float* X      = (const float*)d_in[0];
    const int*   labels = (const int*)d_in[1];
    float*       out    = (float*)d_out;

    char* ws = (char*)d_ws;
    unsigned short* Xb = (unsigned short*)ws;                    // 4 MB
    float* sq   = (float*)(ws + 4194304);                        // 32 KB
    float* vp   = (float*)(ws + 4194304 + 32768);                // 512 KB
    float* vn   = (float*)(ws + 4194304 + 32768 + 524288);       // 512 KB
    float* gsum = (float*)(ws + 4194304 + 32768 + 1048576);      // 12 B

    prep_kernel<<<2048, 256, 0, stream>>>(X, Xb, sq, gsum);
    mine_kernel<<<256, 512, 0, stream>>>(Xb, sq, labels, vp, vn);
    finalize_kernel<<<32, 256, 0, stream>>>(vp, vn, sq, labels, gsum, out);
}